// Round 11
// baseline (93.927 us; speedup 1.0000x reference)
//
#include <hip/hip_runtime.h>

#define S 2000
#define P 2500
#define R 5
#define HALF (S / 2)            // 1000 float4 per gm row
#define ROWS_PER_H 12500        // R*P
#define TOTAL_ROWS 25000
#define TOTAL4 25000000         // total float4 elements across gm0+gm1
#define HTHRESH4 12500000       // float4 index where gm1 begins
#define GM0_OFF4 6250           // float4 offset of gm0 in d_out (100,000 B / 16)
#define GC_GAP4 6250            // float4 gap (gc0, 100,000 B) between gm0 and gm1
#define NWG 768
#define NW (NWG * 4)            // 3072 waves
#define UF 4                    // 64-float4 chunks per wave per iteration

typedef float floatx4 __attribute__((ext_vector_type(4)));

__global__ void zero_flags(unsigned* __restrict__ wsflags) {
    int i = blockIdx.x * 256 + threadIdx.x;
    if (i < TOTAL_ROWS) wsflags[i] = 0u;
}

// Sliding-window writer: all waves sweep [gm0;gm1] in lockstep grid-stride
// order (fill-kernel address pattern -> in-order L2 evictions -> DRAM page
// locality). Each wave-iter writes 4KB contiguous. Row params via uniform
// scalar loads; filtration from LDS; gc flags via wave-OR + atomicOr to ws.
__global__ __launch_bounds__(256) void grad_main(
    const float* __restrict__ filtration,   // (S,2) interleaved
    const float* __restrict__ bars0,        // (P,R)
    const float* __restrict__ bars1,        // (P,R)
    const float* __restrict__ sample_pts,   // (P,2)
    float* __restrict__ obase,              // d_out base (floats)
    unsigned* __restrict__ wsflags)         // 25000 flag words
{
    __shared__ floatx4 sf[HALF];            // 16 KB
    int tid = threadIdx.x;
    const floatx4* filt4 = (const floatx4*)filtration;
    for (int i = tid; i < HALF; i += 256) sf[i] = filt4[i];
    __syncthreads();

    int wid = __builtin_amdgcn_readfirstlane(blockIdx.x * 4 + (tid >> 6));
    int lane = tid & 63;
    floatx4* o4 = (floatx4*)obase;

#pragma unroll 1
    for (int g0 = wid * (UF * 64); g0 < TOTAL4; g0 += NW * UF * 64) {
        // ---- uniform row params for the <=2 rows this 256-float4 window spans
        int rlo = g0 / 1000;
        int jlo = g0 - rlo * 1000;
        int rhi = (g0 + UF * 64 - 1) / 1000;          // rlo or rlo+1

        int hlo = rlo >= ROWS_PER_H;
        int rrlo = rlo - (hlo ? ROWS_PER_H : 0);
        int r_lo = rrlo / P, p_lo = rrlo - (rrlo / P) * P;
        const float* bl = hlo ? bars1 : bars0;
        float bar_lo = bl[p_lo * R + r_lo];
        float ptx_lo = sample_pts[2 * p_lo];
        float pty_lo = sample_pts[2 * p_lo + 1];

        int hhi = rhi >= ROWS_PER_H;
        int rrhi = rhi - (hhi ? ROWS_PER_H : 0);
        int r_hi = rrhi / P, p_hi = rrhi - (rrhi / P) * P;
        const float* bh = hhi ? bars1 : bars0;
        float bar_hi = bh[p_hi * R + r_hi];
        float ptx_hi = sample_pts[2 * p_hi];
        float pty_hi = sample_pts[2 * p_hi + 1];

        unsigned fl_lo = 0u, fl_hi = 0u;

#pragma unroll
        for (int c = 0; c < UF; ++c) {
            int gcb = g0 + 64 * c;                    // uniform
            if (gcb < TOTAL4) {
                int g = gcb + lane;
                int jj = jlo + 64 * c + lane;         // 0..1254
                bool hi = jj >= 1000;
                int j = hi ? jj - 1000 : jj;

                float bar = hi ? bar_hi : bar_lo;
                float ptx = hi ? ptx_hi : ptx_lo;
                float pty = hi ? pty_hi : pty_lo;
                float scale = bar + 0.01f;            // GRID_RES
                float psum = ptx + pty;

                float lxk[5], lyk[5];
#pragma unroll
                for (int k = 0; k < 5; ++k) {
                    float ks = (float)(k - 2) * scale;   // exact mul
                    lxk[k] = ks + ptx;                   // one rounding
                    lyk[k] = ks + pty;
                }
                float lastx = lxk[4];
                float lasty = lyk[4];

                floatx4 f = sf[j];
                floatx4 o;
                unsigned flags = 0u;
                {   // pair 0 (s = 2j)
                    float fx = f.x, fy = f.y;
                    float tolx = __fadd_rn(0.01f, __fmul_rn(1e-5f, __builtin_fabsf(fx)));
                    float toly = __fadd_rn(0.01f, __fmul_rn(1e-5f, __builtin_fabsf(fy)));
                    float mx = fminf(fminf(fminf(__builtin_fabsf(lxk[0] - fx),
                                                 __builtin_fabsf(lxk[1] - fx)),
                                           fminf(__builtin_fabsf(lxk[2] - fx),
                                                 __builtin_fabsf(lxk[3] - fx))),
                                     __builtin_fabsf(lxk[4] - fx));
                    float my = fminf(fminf(fminf(__builtin_fabsf(lyk[0] - fy),
                                                 __builtin_fabsf(lyk[1] - fy)),
                                           fminf(__builtin_fabsf(lyk[2] - fy),
                                                 __builtin_fabsf(lyk[3] - fy))),
                                     __builtin_fabsf(lyk[4] - fy));
                    bool cx = (mx <= tolx) && (fy <= lasty);
                    bool cy = (my <= toly) && (fx <= lastx);
                    float fsum = fx + fy;
                    bool ab = fsum > psum, be = fsum < psum;
                    float sgn = ab ? 1.0f : (be ? -1.0f : 0.0f);
                    o.x = cx ? sgn : 0.0f;
                    o.y = cy ? sgn : 0.0f;
                    flags |= (cx && ab) ? 1u : 0u;  flags |= (cx && be) ? 2u : 0u;
                    flags |= (cy && ab) ? 4u : 0u;  flags |= (cy && be) ? 8u : 0u;
                }
                {   // pair 1 (s = 2j+1)
                    float fx = f.z, fy = f.w;
                    float tolx = __fadd_rn(0.01f, __fmul_rn(1e-5f, __builtin_fabsf(fx)));
                    float toly = __fadd_rn(0.01f, __fmul_rn(1e-5f, __builtin_fabsf(fy)));
                    float mx = fminf(fminf(fminf(__builtin_fabsf(lxk[0] - fx),
                                                 __builtin_fabsf(lxk[1] - fx)),
                                           fminf(__builtin_fabsf(lxk[2] - fx),
                                                 __builtin_fabsf(lxk[3] - fx))),
                                     __builtin_fabsf(lxk[4] - fx));
                    float my = fminf(fminf(fminf(__builtin_fabsf(lyk[0] - fy),
                                                 __builtin_fabsf(lyk[1] - fy)),
                                           fminf(__builtin_fabsf(lyk[2] - fy),
                                                 __builtin_fabsf(lyk[3] - fy))),
                                     __builtin_fabsf(lyk[4] - fy));
                    bool cx = (mx <= tolx) && (fy <= lasty);
                    bool cy = (my <= toly) && (fx <= lastx);
                    float fsum = fx + fy;
                    bool ab = fsum > psum, be = fsum < psum;
                    float sgn = ab ? 1.0f : (be ? -1.0f : 0.0f);
                    o.z = cx ? sgn : 0.0f;
                    o.w = cy ? sgn : 0.0f;
                    flags |= (cx && ab) ? 1u : 0u;  flags |= (cx && be) ? 2u : 0u;
                    flags |= (cy && ab) ? 4u : 0u;  flags |= (cy && be) ? 8u : 0u;
                }
                fl_lo |= hi ? 0u : flags;
                fl_hi |= hi ? flags : 0u;

                int a4 = GM0_OFF4 + g + ((g >= HTHRESH4) ? GC_GAP4 : 0);
                o4[a4] = o;
            }
        }

        // wave OR-reduce of (fl_lo | fl_hi<<4), then <=2 atomics per iter
        unsigned comb = fl_lo | (fl_hi << 4);
#pragma unroll
        for (int m = 1; m < 64; m <<= 1)
            comb |= (unsigned)__shfl_xor((int)comb, m);
        if (lane == 0) {
            unsigned lo = comb & 0xFu;
            unsigned hi = (comb >> 4) & 0xFu;
            if (lo) atomicOr(&wsflags[rlo], lo);
            if (hi) atomicOr(&wsflags[rhi], hi);
        }
    }
}

__global__ void finalize(const float* __restrict__ bars0,
                         const float* __restrict__ bars1,
                         const unsigned* __restrict__ wsflags,
                         float* __restrict__ obase)
{
    int i = blockIdx.x * 256 + threadIdx.x;
    if (i >= TOTAL_ROWS) return;
    int h = i >= ROWS_PER_H;
    int rr = i - (h ? ROWS_PER_H : 0);
    int r = rr / P, p = rr - r * P;
    unsigned b = wsflags[i];
    float cxv = (b & 1u) ? -1.0f : ((b & 2u) ? 1.0f : 0.0f);
    float cyv = (b & 4u) ? -1.0f : ((b & 8u) ? 1.0f : 0.0f);
    float* gc = obase + (h ? 100050000 : 50025000);   // gc1 / gc0 float offsets
    gc[rr * 2] = cxv;
    gc[rr * 2 + 1] = cyv;
    // out[h][p][r] = bar
    obase[h * (P * R) + p * R + r] = (h ? bars1 : bars0)[p * R + r];
}

extern "C" void kernel_launch(void* const* d_in, const int* in_sizes, int n_in,
                              void* d_out, int out_size, void* d_ws, size_t ws_size,
                              hipStream_t stream) {
    const float* filtration = (const float*)d_in[0];   // (2000,2)
    const float* bars_h0    = (const float*)d_in[1];   // (2500,5)
    const float* bars_h1    = (const float*)d_in[2];   // (2500,5)
    const float* sample_pts = (const float*)d_in[3];   // (2500,2)

    float* obase = (float*)d_out;
    unsigned* wsflags = (unsigned*)d_ws;               // 25000 u32 = 100 KB

    zero_flags<<<(TOTAL_ROWS + 255) / 256, 256, 0, stream>>>(wsflags);
    grad_main<<<NWG, 256, 0, stream>>>(filtration, bars_h0, bars_h1, sample_pts,
                                       obase, wsflags);
    finalize<<<(TOTAL_ROWS + 255) / 256, 256, 0, stream>>>(bars_h0, bars_h1,
                                                           wsflags, obase);
}